// Round 1
// baseline (836.534 us; speedup 1.0000x reference)
//
#include <hip/hip_runtime.h>

// Bilinear flow warp: input1 [B,C,H,W] fp32, input2 [B,2,H,W] flow (dx,dy).
// out[b,c,i,j] = bilinear sample of input1[b,c] at (i+fy, j+fx), OOB -> 0.
//
// Shapes fixed by the reference harness.
constexpr int B = 8, C = 64, H = 256, W = 448;
constexpr int HW = H * W;          // 114688
constexpr int NPIX = B * HW;       // 917504

__global__ __launch_bounds__(256) void warp_kernel(
    const float* __restrict__ img,   // [B,C,H,W]
    const float* __restrict__ flow,  // [B,2,H,W]
    float* __restrict__ out)         // [B,C,H,W]
{
    int pix = blockIdx.x * blockDim.x + threadIdx.x;
    if (pix >= NPIX) return;

    int b  = pix / HW;
    int ij = pix - b * HW;
    int i  = ij / W;
    int j  = ij - i * W;

    // flow for this pixel (coalesced: lanes are consecutive j)
    float fx = flow[(size_t)(b * 2 + 0) * HW + ij];
    float fy = flow[(size_t)(b * 2 + 1) * HW + ij];

    float x = (float)j + fx;
    float y = (float)i + fy;

    float x0f = floorf(x), y0f = floorf(y);
    int   x0  = (int)x0f,  y0  = (int)y0f;
    float wx1 = x - x0f,   wy1 = y - y0f;
    float wx0 = 1.0f - wx1, wy0 = 1.0f - wy1;

    // per-corner validity (matches reference: valid iff 0 <= coord <= dim-1)
    bool vx0 = (x0 >= 0)     & (x0 <= W - 1);
    bool vx1 = (x0 >= -1)    & (x0 <= W - 2);
    bool vy0 = (y0 >= 0)     & (y0 <= H - 1);
    bool vy1 = (y0 >= -1)    & (y0 <= H - 2);

    float w00 = (vy0 & vx0) ? wy0 * wx0 : 0.0f;
    float w01 = (vy0 & vx1) ? wy0 * wx1 : 0.0f;
    float w10 = (vy1 & vx0) ? wy1 * wx0 : 0.0f;
    float w11 = (vy1 & vx1) ? wy1 * wx1 : 0.0f;

    // clamped gather indices (weight already zero when OOB)
    int xi0 = min(max(x0, 0),     W - 1);
    int xi1 = min(max(x0 + 1, 0), W - 1);
    int yi0 = min(max(y0, 0),     H - 1);
    int yi1 = min(max(y0 + 1, 0), H - 1);

    int o00 = yi0 * W + xi0;
    int o01 = yi0 * W + xi1;
    int o10 = yi1 * W + xi0;
    int o11 = yi1 * W + xi1;

    const float* ib = img + (size_t)b * C * HW;
    float*       ob = out + (size_t)b * C * HW + ij;

    // channel loop: weights/indices reused across all 64 channels.
    // 4 gather loads + 1 coalesced store per channel; unroll for MLP/ILP.
    #pragma unroll 8
    for (int c = 0; c < C; ++c) {
        const float* p = ib + (size_t)c * HW;
        float v = w00 * p[o00] + w01 * p[o01]
                + w10 * p[o10] + w11 * p[o11];
        ob[(size_t)c * HW] = v;
    }
}

extern "C" void kernel_launch(void* const* d_in, const int* in_sizes, int n_in,
                              void* d_out, int out_size, void* d_ws, size_t ws_size,
                              hipStream_t stream) {
    const float* img  = (const float*)d_in[0];
    const float* flow = (const float*)d_in[1];
    float* out = (float*)d_out;

    dim3 block(256);
    dim3 grid((NPIX + 255) / 256);
    warp_kernel<<<grid, block, 0, stream>>>(img, flow, out);
}

// Round 2
// 642.136 us; speedup vs baseline: 1.3027x; 1.3027x over previous
//
#include <hip/hip_runtime.h>

// Bilinear flow warp: input1 [B,C,H,W] fp32, input2 [B,2,H,W] flow (dx,dy).
// out[b,c,i,j] = bilinear sample of input1[b,c] at (i+fy, j+fx), OOB -> 0.
constexpr int B = 8, C = 64, H = 256, W = 448;
constexpr int HW = H * W;          // 114688
constexpr int NPIX = B * HW;       // 917504
constexpr int BLK = 256;
constexpr int NBLOCKS = NPIX / BLK;        // 3584
constexpr int XCDS = 8;
constexpr int BLOCKS_PER_XCD = NBLOCKS / XCDS;  // 448 == blocks per batch image

__global__ __launch_bounds__(256) void warp_kernel(
    const float* __restrict__ img,   // [B,C,H,W]
    const float* __restrict__ flow,  // [B,2,H,W]
    float* __restrict__ out)         // [B,C,H,W]
{
    // XCD-aware swizzle: consecutive blockIdx round-robin across 8 XCDs
    // (private L2s). Remap so each XCD processes one contiguous batch image;
    // the +/-12-row gather-reuse band then stays inside one XCD's 4MB L2.
    int bid = blockIdx.x;
    int swz = (bid % XCDS) * BLOCKS_PER_XCD + (bid / XCDS);
    int pix = swz * BLK + threadIdx.x;

    int b  = pix / HW;
    int ij = pix - b * HW;
    int i  = ij / W;
    int j  = ij - i * W;

    // flow for this pixel (coalesced: lanes are consecutive j)
    float fx = flow[(size_t)(b * 2 + 0) * HW + ij];
    float fy = flow[(size_t)(b * 2 + 1) * HW + ij];

    float x = (float)j + fx;
    float y = (float)i + fy;

    float x0f = floorf(x), y0f = floorf(y);
    int   x0  = (int)x0f,  y0  = (int)y0f;
    float wx1 = x - x0f,   wy1 = y - y0f;
    float wx0 = 1.0f - wx1, wy0 = 1.0f - wy1;

    // per-corner validity (matches reference: valid iff 0 <= coord <= dim-1)
    bool vx0 = (x0 >= 0)  & (x0 <= W - 1);
    bool vx1 = (x0 >= -1) & (x0 <= W - 2);
    bool vy0 = (y0 >= 0)  & (y0 <= H - 1);
    bool vy1 = (y0 >= -1) & (y0 <= H - 2);

    float w00 = (vy0 & vx0) ? wy0 * wx0 : 0.0f;
    float w01 = (vy0 & vx1) ? wy0 * wx1 : 0.0f;
    float w10 = (vy1 & vx0) ? wy1 * wx0 : 0.0f;
    float w11 = (vy1 & vx1) ? wy1 * wx1 : 0.0f;

    // clamped gather indices (weight already zero when OOB)
    int xi0 = min(max(x0, 0),     W - 1);
    int xi1 = min(max(x0 + 1, 0), W - 1);
    int yi0 = min(max(y0, 0),     H - 1);
    int yi1 = min(max(y0 + 1, 0), H - 1);

    int o00 = yi0 * W + xi0;
    int o01 = yi0 * W + xi1;
    int o10 = yi1 * W + xi0;
    int o11 = yi1 * W + xi1;

    const float* ib = img + (size_t)b * C * HW;
    float*       ob = out + (size_t)b * C * HW + ij;

    // Channel loop, batched 8 at a time: issue 32 gather loads back-to-back
    // (memory-level parallelism), then combine + coalesced store.
    #pragma unroll
    for (int cb = 0; cb < C; cb += 8) {
        float v00[8], v01[8], v10[8], v11[8];
        #pragma unroll
        for (int u = 0; u < 8; ++u) {
            const float* q = ib + (size_t)(cb + u) * HW;
            v00[u] = q[o00];
            v01[u] = q[o01];
            v10[u] = q[o10];
            v11[u] = q[o11];
        }
        #pragma unroll
        for (int u = 0; u < 8; ++u) {
            ob[(size_t)(cb + u) * HW] =
                w00 * v00[u] + w01 * v01[u] + w10 * v10[u] + w11 * v11[u];
        }
    }
}

extern "C" void kernel_launch(void* const* d_in, const int* in_sizes, int n_in,
                              void* d_out, int out_size, void* d_ws, size_t ws_size,
                              hipStream_t stream) {
    const float* img  = (const float*)d_in[0];
    const float* flow = (const float*)d_in[1];
    float* out = (float*)d_out;

    warp_kernel<<<dim3(NBLOCKS), dim3(BLK), 0, stream>>>(img, flow, out);
}